// Round 9
// baseline (2345.314 us; speedup 1.0000x reference)
//
#include <hip/hip_runtime.h>

// Problem constants (SIZE=68, SSN=8 -> C=9, S1=69, BATCH=256)
#define C9     9
#define S1     69
#define JT     621            // C9*S1: one (class,pos) plane
#define NBATCH 256
#define NSTEP  68
#define QJ     4761           // 69*69
#define QI     42849          // 9*69*69 (Q j-stride in QW; P batch stride)
#define BROW   42849
#define ALPHA_N (NBATCH*BROW)
#define QTFL   385664         // padded float count of QW / QT region
#define XCSTR  672            // floats per (group,parity,chunk) exchange slot
#define XCFL   (64*2*4*XCSTR) // 344064 floats
#define FLAGN  4608           // 64 groups * 72 flags
#define NEGINF (-__builtin_inff())

typedef float float2u  __attribute__((ext_vector_type(2), aligned(4)));
typedef float float4a  __attribute__((ext_vector_type(4), aligned(16)));

#define AGENT __HIP_MEMORY_SCOPE_AGENT

// LDS-only barrier (orders LDS via lgkmcnt; rule-18 sched fences).
__device__ __forceinline__ void barrier_lgkm()
{
  __builtin_amdgcn_sched_barrier(0);
  asm volatile("s_waitcnt lgkmcnt(0)" ::: "memory");
  __builtin_amdgcn_s_barrier();
  __builtin_amdgcn_sched_barrier(0);
}

// ---------------------------------------------------------------------------
// qw: QW[j][s][i][t] = Q[j][i][s][t].
__global__ void qw_kernel(const float* __restrict__ Q, float* __restrict__ QW)
{
  const int bl = blockIdx.x;           // j*69 + s
  const int j = bl / S1, s = bl - j*S1;
  float* dst = QW + (size_t)bl*JT;
  const float* src = Q + (size_t)j*QJ + s*S1;
  for (int f = threadIdx.x; f < JT; f += 256){
    const int i = f / S1, t = f - i*S1;
    dst[f] = src[i*QJ + t];
  }
}

// qtrans: QT[c][t][i][s] = Q[c][i][s][t]  (coalesced backtrace Q reads)
__global__ void qtrans_kernel(const float* __restrict__ Q, float* __restrict__ QT)
{
  __shared__ float tile[69*70];
  const int pl = blockIdx.x;           // c*9 + i
  const int c = pl / 9, i = pl - c*9;
  const float* src = Q + (size_t)pl*QJ;
  for (int f = threadIdx.x; f < QJ; f += 256){
    const int s = f / S1, t = f - s*S1;
    tile[s*70 + t] = src[f];
  }
  __syncthreads();
  float* dst = QT + (size_t)c*QI + i*S1;
  for (int f = threadIdx.x; f < QJ; f += 256){
    const int t = f / S1, s = f - t*S1;
    dst[t*JT + s] = tile[s*70 + t];
  }
}

// zero the sync flags with agent-scope stores (coherent at the IC --
// a plain memset could leave stale values at the coherence point).
__global__ void zf_kernel(unsigned* __restrict__ f)
{
  const int i = blockIdx.x*256 + threadIdx.x;
  if (i < FLAGN) __hip_atomic_store(&f[i], 0u, __ATOMIC_RELAXED, AGENT);
}

// ---------------------------------------------------------------------------
// mega_group: 64 groups x 4 chunk-blocks.  Block (g,h) computes t-chunk h of
// v[k] for batches 4g..4g+3, sharing ONE Q stream across the 4 batches in
// registers.  Per-CU per-step L2 traffic drops from ~1.7MB to ~0.56MB -- the
// measured per-CU fill-rate wall (~55GB/s, invariant across r2/r7/r8) is the
// bottleneck, so bytes/CU is the only lever.  Chunk c-planes are exchanged
// per step via agent-scope (IC-coherent) stores + per-group flag sync.
// Grid 256 = 1 block/CU (guide-sanctioned co-residency with launch_bounds).
__global__ __launch_bounds__(704) void mega_group(
    const float* __restrict__ P, const float* __restrict__ Q,
    const float* __restrict__ pi, const float* __restrict__ Tp,
    const int* __restrict__ ls, float* __restrict__ out,
    const float* __restrict__ QW, const float* __restrict__ QT,
    float* __restrict__ XC, unsigned* __restrict__ FLAGS, int qtmode)
{
  __shared__ __align__(16) float la4[C9*70*4];        // [i][s pad 70][m]
  __shared__ __align__(16) float part[7][81][8];      // s-groups 1..7 partials
  __shared__ float cbuf[4][624];                      // full c-plane, 4 batches
  __shared__ float msh[NSTEP+1][4];                   // v-space max per batch
  __shared__ float sums_sh[NSTEP+1][11][4];           // per-wave exp sums
  __shared__ float mpart[2][4];
  __shared__ float lse_sh[NSTEP+1], n_sh[NSTEP+1];
  __shared__ float lse0_sh;
  __shared__ float sbest[11];
  __shared__ int   sidx[11];
  __shared__ int   sct[2];

  const int tid  = threadIdx.x;
  const int w    = tid >> 6, lane = tid & 63;
  const int g    = blockIdx.x >> 2, h = blockIdx.x & 3;
  const int Th   = h ? 17 : 18;
  const int Bh   = h ? (18 + 17*(h-1)) : 0;           // {0,18,35,52}
  const bool act = tid < 648;
  const int sg   = act ? tid / 81 : 7;                // s-group 0..7
  const int slot = act ? tid - sg*81 : 80;
  const int j    = slot / 9;
  const int tp   = slot - j*9;                        // t-pair 0..8
  const bool own2 = (2*tp + 1 < Th);                  // Th=17,tp=8: single
  const int tl0  = own2 ? 2*tp : (Th-2);              // pair = tl0, tl0+1 (in-chunk)
  const int tg0  = Bh + tl0;
  const int Ws   = (sg < 7) ? 9 : 6;                  // s-widths partition 69
  const int s_lo = sg*9;
  const float Tv = Tp[0];
  const int bb   = 4*g + h;                           // epilogue batch
  unsigned* flg  = FLAGS + g*72;

  // ---- prep: la4 = v[0] raw; alpha plane 68 (my chunk, 4 batches) ----
  for (int e = tid; e < JT; e += 704){
    const int ii = e / 69, ss = e - ii*69;
    const float v0 = (ss == 0) ? pi[ii] : NEGINF;
    float4a vv; vv.x = vv.y = vv.z = vv.w = v0;
    *(float4a*)(&la4[(ii*70 + ss)*4]) = vv;
  }
  for (int idx = tid; idx < 4*9*Th; idx += 704){
    const int m = idx / (9*Th); const int rem = idx - m*(9*Th);
    const int jj = rem / Th;    const int tl = rem - jj*Th;
    const int t = Bh + tl;
    out[(size_t)(4*g+m)*BROW + 68*JT + jj*69 + t] = (t == 0) ? pi[jj] : NEGINF;
  }
  if (tid == 0){
    float mx = pi[0];
    #pragma unroll
    for (int c = 1; c < C9; ++c) mx = fmaxf(mx, pi[c]);
    float sm = 0.f;
    #pragma unroll
    for (int c = 0; c < C9; ++c) sm += expf(pi[c] - mx);
    #pragma unroll
    for (int m = 0; m < 4; ++m) msh[0][m] = mx;
    lse0_sh = mx + logf(sm);
  }
  __syncthreads();
  float mprev0 = msh[0][0], mprev1 = msh[0][1], mprev2 = msh[0][2], mprev3 = msh[0][3];

  // bases: QW[j][s][i][t]; P[b][j][s][t]
  const float* qb  = QW + (size_t)j*QI + (size_t)s_lo*JT + tg0;
  const float* pb0 = P + (size_t)((4*g+0)*C9 + j)*QJ + s_lo*S1 + tg0;
  const float* pb1 = pb0 + QI;
  const float* pb2 = pb1 + QI;
  const float* pb3 = pb2 + QI;

#define GLD(B, D) { \
  const float* q_ = qb + (size_t)(D)*JT; \
  _Pragma("unroll") \
  for (int i_ = 0; i_ < 9; ++i_) B[i_] = *(const float2u*)(q_ + i_*S1); }

#define GCM(B, D) { \
  const int sa_ = s_lo + (D); \
  const float2u pv0 = *(const float2u*)(pb0 + (D)*S1); \
  const float2u pv1 = *(const float2u*)(pb1 + (D)*S1); \
  const float2u pv2 = *(const float2u*)(pb2 + (D)*S1); \
  const float2u pv3 = *(const float2u*)(pb3 + (D)*S1); \
  float2u r0, r1, r2, r3; \
  r0.x=r0.y=r1.x=r1.y=r2.x=r2.y=r3.x=r3.y=NEGINF; \
  _Pragma("unroll") \
  for (int i_ = 0; i_ < 9; ++i_){ \
    const float4a lv = *(const float4a*)(&la4[(i_*70 + sa_)*4]); \
    const float qx = B[i_].x, qy = B[i_].y; \
    r0.x=fmaxf(r0.x,fmaf(Tv,qx,lv.x)); r0.y=fmaxf(r0.y,fmaf(Tv,qy,lv.x)); \
    r1.x=fmaxf(r1.x,fmaf(Tv,qx,lv.y)); r1.y=fmaxf(r1.y,fmaf(Tv,qy,lv.y)); \
    r2.x=fmaxf(r2.x,fmaf(Tv,qx,lv.z)); r2.y=fmaxf(r2.y,fmaf(Tv,qy,lv.z)); \
    r3.x=fmaxf(r3.x,fmaf(Tv,qx,lv.w)); r3.y=fmaxf(r3.y,fmaf(Tv,qy,lv.w)); \
  } \
  acc0.x=fmaxf(acc0.x,pv0.x+r0.x); acc0.y=fmaxf(acc0.y,pv0.y+r0.y); \
  acc1.x=fmaxf(acc1.x,pv1.x+r1.x); acc1.y=fmaxf(acc1.y,pv1.y+r1.y); \
  acc2.x=fmaxf(acc2.x,pv2.x+r2.x); acc2.y=fmaxf(acc2.y,pv2.y+r2.y); \
  acc3.x=fmaxf(acc3.x,pv3.x+r3.x); acc3.y=fmaxf(acc3.y,pv3.y+r3.y); }

  // ---- 68 max-plus steps ----
  for (int k = 1; k <= NSTEP; ++k){
    float2u acc0, acc1, acc2, acc3;
    acc0.x=acc0.y=acc1.x=acc1.y=acc2.x=acc2.y=acc3.x=acc3.y=NEGINF;
    if (act){
      float2u qA[9], qB[9];
      GLD(qA, 0)
      int d = 0;
      for (; d + 2 < Ws; d += 2){
        GLD(qB, d+1)  GCM(qA, d)  GLD(qA, d+2)  GCM(qB, d+1)
      }
      if (d + 1 < Ws){ GLD(qB, d+1) GCM(qA, d) GCM(qB, d+1) }
      else { GCM(qA, d) }
      if (sg > 0){
        float4a u0; u0.x=acc0.x; u0.y=acc0.y; u0.z=acc1.x; u0.w=acc1.y;
        float4a u1; u1.x=acc2.x; u1.y=acc2.y; u1.z=acc3.x; u1.w=acc3.y;
        *(float4a*)(&part[sg-1][slot][0]) = u0;
        *(float4a*)(&part[sg-1][slot][4]) = u1;
      }
    }
    barrier_lgkm();                                    // (A) partials ready

    float* xcm = XC + (size_t)(((g*2 + (k&1))*4) + h)*XCSTR;
    float cm0=NEGINF, cm1=NEGINF, cm2=NEGINF, cm3=NEGINF;
    if (act && sg == 0){
      float2u c0=acc0, c1=acc1, c2=acc2, c3=acc3;
      #pragma unroll
      for (int gq = 0; gq < 7; ++gq){
        const float4a t0 = *(const float4a*)(&part[gq][slot][0]);
        const float4a t1 = *(const float4a*)(&part[gq][slot][4]);
        c0.x=fmaxf(c0.x,t0.x); c0.y=fmaxf(c0.y,t0.y);
        c1.x=fmaxf(c1.x,t0.z); c1.y=fmaxf(c1.y,t0.w);
        c2.x=fmaxf(c2.x,t1.x); c2.y=fmaxf(c2.y,t1.y);
        c3.x=fmaxf(c3.x,t1.z); c3.y=fmaxf(c3.y,t1.w);
      }
      const int colbase = j*69 + tg0;
      const int pubj = j*Th + tl0;
#define EMIT(MB, CC, MPREV, CM) { \
      const float vx = CC.x - (MPREV), vy = CC.y - (MPREV); \
      float* dst = out + (size_t)(4*g+MB)*BROW + (size_t)(68-k)*JT + colbase; \
      const int pb_ = MB*9*Th + pubj; \
      if (own2){ \
        float2u vv; vv.x=vx; vv.y=vy; *(float2u*)dst = vv; \
        cbuf[MB][colbase] = CC.x; cbuf[MB][colbase+1] = CC.y; \
        __hip_atomic_store(xcm + pb_,     CC.x, __ATOMIC_RELAXED, AGENT); \
        __hip_atomic_store(xcm + pb_ + 1, CC.y, __ATOMIC_RELAXED, AGENT); \
        CM = fmaxf(CC.x, CC.y); \
      } else { \
        dst[1] = vy; \
        cbuf[MB][colbase+1] = CC.y; \
        __hip_atomic_store(xcm + pb_ + 1, CC.y, __ATOMIC_RELAXED, AGENT); \
        CM = CC.y; \
      } }
      EMIT(0, c0, mprev0, cm0)
      EMIT(1, c1, mprev1, cm1)
      EMIT(2, c2, mprev2, cm2)
      EMIT(3, c3, mprev3, cm3)
#undef EMIT
    }
    // chunk-max wave reduce (g0 lives in waves 0..1)
    float mv0 = cm0, mv1 = cm1, mv2 = cm2, mv3 = cm3;
    #pragma unroll
    for (int o = 32; o >= 1; o >>= 1){
      mv0 = fmaxf(mv0, __shfl_down(mv0, o));
      mv1 = fmaxf(mv1, __shfl_down(mv1, o));
      mv2 = fmaxf(mv2, __shfl_down(mv2, o));
      mv3 = fmaxf(mv3, __shfl_down(mv3, o));
    }
    if (lane == 0 && w < 2){
      mpart[w][0]=mv0; mpart[w][1]=mv1; mpart[w][2]=mv2; mpart[w][3]=mv3;
    }
    __syncthreads();                                   // (PUB) drains stores

    unsigned* flagk = flg + k;
    if (tid == 0){
      #pragma unroll
      for (int m = 0; m < 4; ++m){
        const float mm = fmaxf(mpart[0][m], mpart[1][m]);
        __hip_atomic_store(xcm + 656 + m, mm, __ATOMIC_RELAXED, AGENT);
      }
      asm volatile("s_waitcnt vmcnt(0)" ::: "memory");
      __hip_atomic_fetch_add(flagk, 1u, __ATOMIC_RELEASE, AGENT);
      int it = 0;
      while (__hip_atomic_load(flagk, __ATOMIC_RELAXED, AGENT) < 4u){
        __builtin_amdgcn_s_sleep(2);
        if (++it > 3000000) break;                     // safety (never hit)
      }
      (void)__hip_atomic_load(flagk, __ATOMIC_ACQUIRE, AGENT);
      float q0=NEGINF, q1=NEGINF, q2=NEGINF, q3=NEGINF;
      #pragma unroll
      for (int hh = 0; hh < 4; ++hh){                  // fixed h-order: exact
        const float* src = XC + (size_t)(((g*2 + (k&1))*4) + hh)*XCSTR + 656;
        q0 = fmaxf(q0, __hip_atomic_load(src + 0, __ATOMIC_RELAXED, AGENT));
        q1 = fmaxf(q1, __hip_atomic_load(src + 1, __ATOMIC_RELAXED, AGENT));
        q2 = fmaxf(q2, __hip_atomic_load(src + 2, __ATOMIC_RELAXED, AGENT));
        q3 = fmaxf(q3, __hip_atomic_load(src + 3, __ATOMIC_RELAXED, AGENT));
      }
      msh[k][0] = q0 - mprev0;  msh[k][1] = q1 - mprev1;
      msh[k][2] = q2 - mprev2;  msh[k][3] = q3 - mprev3;
    }
    barrier_lgkm();                                    // (POSTSPIN)

    // pull 3 partner c-chunks into cbuf (one element per thread per chunk)
    #pragma unroll
    for (int hh = 0; hh < 4; ++hh){
      if (hh == h) continue;
      const int Whh = hh ? 17 : 18;
      const int Bhh = hh ? (18 + 17*(hh-1)) : 0;
      const int n = 36*Whh;
      if (tid < n){
        const float* src = XC + (size_t)(((g*2 + (k&1))*4) + hh)*XCSTR;
        const int m = tid / (9*Whh); const int rem = tid - m*(9*Whh);
        const int jj = rem / Whh;    const int tl = rem - jj*Whh;
        cbuf[m][jj*69 + Bhh + tl] = __hip_atomic_load(src + tid, __ATOMIC_RELAXED, AGENT);
      }
    }
    barrier_lgkm();                                    // (C) cbuf + msh ready

    const float mk0 = msh[k][0], mk1 = msh[k][1], mk2 = msh[k][2], mk3 = msh[k][3];
    float s0 = 0.f, s1 = 0.f, s2 = 0.f, s3 = 0.f;
    if (tid < JT){
      const int ii = tid / 69, ss = tid - ii*69;
      const float v0 = cbuf[0][tid] - mprev0;
      const float v1 = cbuf[1][tid] - mprev1;
      const float v2 = cbuf[2][tid] - mprev2;
      const float v3 = cbuf[3][tid] - mprev3;
      float4a vv; vv.x=v0; vv.y=v1; vv.z=v2; vv.w=v3;
      *(float4a*)(&la4[(ii*70 + ss)*4]) = vv;
      s0 = expf(v0 - mk0); s1 = expf(v1 - mk1);
      s2 = expf(v2 - mk2); s3 = expf(v3 - mk3);
    }
    #pragma unroll
    for (int o = 32; o >= 1; o >>= 1){
      s0 += __shfl_down(s0, o); s1 += __shfl_down(s1, o);
      s2 += __shfl_down(s2, o); s3 += __shfl_down(s3, o);
    }
    if (lane == 0){
      sums_sh[k][w][0]=s0; sums_sh[k][w][1]=s1;
      sums_sh[k][w][2]=s2; sums_sh[k][w][3]=s3;
    }
    mprev0 = mk0; mprev1 = mk1; mprev2 = mk2; mprev3 = mk3;
    barrier_lgkm();                                    // (D) la4 ready
  }

  // ---- final cross-block visibility (alpha planes were normal stores) ----
  __syncthreads();
  if (tid == 0){
    __threadfence();
    unsigned* flagF = flg + 69;
    __hip_atomic_fetch_add(flagF, 1u, __ATOMIC_RELEASE, AGENT);
    int it = 0;
    while (__hip_atomic_load(flagF, __ATOMIC_RELAXED, AGENT) < 4u){
      __builtin_amdgcn_s_sleep(2);
      if (++it > 3000000) break;
    }
    (void)__hip_atomic_load(flagF, __ATOMIC_ACQUIRE, AGENT);
  }
  __syncthreads();

  // ---- epilogue for batch bb = 4g+h ----
  float* outb = out + (size_t)bb*BROW;
  if (tid == 0){
    double dd = 0.0;
    for (int kk = 0; kk <= NSTEP; ++kk){
      float lse;
      if (kk == 0) lse = lse0_sh;
      else {
        float S = 0.f;
        #pragma unroll
        for (int q = 0; q < 11; ++q) S += sums_sh[kk][q][h];
        lse = msh[kk][h] + logf(S);
      }
      lse_sh[kk] = lse;
      n_sh[kk] = (float)((double)lse + dd);
      dd += (double)msh[kk][h];
    }
  }
  __syncthreads();

  for (int K = 0; K <= NSTEP; ++K){
    const float Cst = n_sh[K] - lse_sh[68-K];
    for (int e = tid; e < JT; e += 704){
      float* r = outb + (size_t)K*JT + e;
      *r = fmaxf(*r + Cst, -3.0e38f);
    }
  }
  __syncthreads();

  { // backtrace (exact ref association; first-occurrence argmax)
    int c = 3, t2 = ls[bb];
    float* mpb = out + (size_t)ALPHA_N + (size_t)bb*(69*3);
    if (tid == 0){
      mpb[68*3+0] = 3.f; mpb[68*3+1] = 0.f; mpb[68*3+2] = (float)t2;
      mpb[67*3+1] = 0.f;
    }
    const bool vok = tid < JT;
    const int etid = vok ? tid : 0;
    const int im = etid / S1;
    const int sm = etid - im*S1;
    float av = vok ? outb[1*JT + tid] : NEGINF;
    for (int r = 1; r <= NSTEP; ++r){
      float avn = NEGINF;
      if (r < NSTEP && vok) avn = outb[(size_t)(r+1)*JT + tid];
      float best = NEGINF; int bidx = 0x7fffffff;
      if (vok){
        float qv;
        if (qtmode >= 2) qv = QT[(size_t)c*QI + (size_t)t2*JT + tid];
        else             qv = QW[(size_t)c*QI + (size_t)sm*JT + im*S1 + t2];
        const float pv = P[(size_t)(bb*C9 + c)*QJ + sm*S1 + t2];
        best = (pv + Tv*qv) + av;
        bidx = tid;
      }
      #pragma unroll
      for (int o = 32; o >= 1; o >>= 1){
        const float ov = __shfl_down(best, o); const int oi = __shfl_down(bidx, o);
        if (ov > best || (ov == best && oi < bidx)){ best = ov; bidx = oi; }
      }
      if (lane == 0){ sbest[w] = best; sidx[w] = bidx; }
      __syncthreads();
      if (tid == 0){
        float bbv = sbest[0]; int bi = sidx[0];
        #pragma unroll
        for (int q = 1; q < 11; ++q)
          if (sbest[q] > bbv || (sbest[q] == bbv && sidx[q] < bi)){
            bbv = sbest[q]; bi = sidx[q];
          }
        const int cn = bi / S1, tn = bi - cn*S1;
        mpb[(68-r)*3 + 0] = (float)cn;
        mpb[(68-r)*3 + 2] = (float)tn;
        if (r <= 67) mpb[(67-r)*3 + 1] = (float)(tn - t2);
        sct[0] = cn; sct[1] = tn;
      }
      __syncthreads();
      c = sct[0]; t2 = sct[1];
      av = avn;
    }
  }
}

// ---------------------------------------------------------------------------
// Fallback (r8 structure, proven): used only if ws too small for group mode.
__global__ __launch_bounds__(704) void mega_fb(
    const float* __restrict__ P, const float* __restrict__ Q,
    const float* __restrict__ pi, const float* __restrict__ Tp,
    const int* __restrict__ ls, float* __restrict__ out,
    const float* __restrict__ QW, int wsmode)
{
  __shared__ __align__(16) float la[2][C9*72];
  __shared__ float part[315][3];
  __shared__ float red[11];
  __shared__ float m_sh[NSTEP+1], lse_sh[NSTEP+1], n_sh[NSTEP+1];
  __shared__ float sums_sh[NSTEP+1][5];
  __shared__ float sbest[11];
  __shared__ int   sidx[11];
  __shared__ int   sct[2];

  const int tid = threadIdx.x, w = tid>>6, lane = tid&63, b = blockIdx.x;
  const bool act = tid < 630;
  const int gg = act ? tid/315 : 1;
  const int slot = act ? tid - gg*315 : 314;
  const int j = slot/35, tp = slot - j*35;
  const bool own2 = (tp < 34);
  const int t0 = own2 ? 2*tp : 67;
  const int s_lo = gg*34;
  const float Tv = Tp[0];
  float* outb = out + (size_t)b*BROW;

  for (int e = tid; e < JT; e += 704){
    const int i = e/S1, s = e - i*S1;
    const float v0i = (s==0)? pi[i] : NEGINF;
    outb[68*JT + e] = v0i;
    la[0][i*72 + s] = v0i;
  }
  if (tid == 0){
    float mx = pi[0];
    #pragma unroll
    for (int c = 1; c < C9; ++c) mx = fmaxf(mx, pi[c]);
    float sm = 0.f;
    #pragma unroll
    for (int c = 0; c < C9; ++c) sm += expf(pi[c]-mx);
    m_sh[0] = mx;  lse_sh[0] = mx + logf(sm);
  }
  __syncthreads();
  float mprev = m_sh[0];
  const bool useQW = (wsmode >= 1);
  const float* qb = useQW ? (QW + (size_t)j*QI + (size_t)s_lo*JT + t0)
                          : (Q  + (size_t)j*QJ + s_lo*S1 + t0);
  const float* pb = P + (size_t)(b*C9 + j)*QJ + s_lo*S1 + t0;
  const int SIv = useQW ? S1 : QI;
  const int SSv = useQW ? JT : S1;

  for (int k = 1; k <= NSTEP; ++k){
    const float* laC = la[(k-1)&1];
    float accx = NEGINF, accy = NEGINF;
    if (act){
      float2u qA[9], qB[9];
      #define FLD(B, D) { const float* q_ = qb + (size_t)(D)*SSv; \
        _Pragma("unroll") for (int i_=0;i_<9;++i_) B[i_] = *(const float2u*)(q_ + i_*SIv); }
      #define FCM(B, D) { const float2u pv_ = *(const float2u*)(pb + (D)*S1); \
        float r0=NEGINF, r1=NEGINF; \
        _Pragma("unroll") for (int i_=0;i_<9;++i_){ \
          const float lv_ = laC[i_*72 + s_lo + (D)]; \
          r0 = fmaxf(r0, fmaf(Tv, B[i_].x, lv_)); \
          r1 = fmaxf(r1, fmaf(Tv, B[i_].y, lv_)); } \
        accx = fmaxf(accx, pv_.x + r0); accy = fmaxf(accy, pv_.y + r1); }
      FLD(qA, 0)
      int d = 0;
      for (; d + 2 < 35; d += 2){ FLD(qB,d+1) FCM(qA,d) FLD(qA,d+2) FCM(qB,d+1) }
      FCM(qA, 34)
      #undef FLD
      #undef FCM
      if (gg == 1){ part[slot][0] = accx; part[slot][1] = accy; }
    }
    barrier_lgkm();
    float mval = NEGINF, v0 = 0.f, v1 = 0.f;
    if (act && gg == 0){
      v0 = fmaxf(accx, part[slot][0]) - mprev;
      v1 = fmaxf(accy, part[slot][1]) - mprev;
      float* dst = outb + (size_t)(68-k)*JT + j*S1 + t0;
      if (own2){
        float2u vv; vv.x=v0; vv.y=v1; *(float2u*)dst = vv;
        la[k&1][j*72 + t0] = v0; la[k&1][j*72 + t0 + 1] = v1;
        mval = fmaxf(v0, v1);
      } else { dst[1] = v1; la[k&1][j*72 + 68] = v1; mval = v1; }
    }
    float mr = mval;
    #pragma unroll
    for (int o = 32; o >= 1; o >>= 1) mr = fmaxf(mr, __shfl_down(mr, o));
    if (lane == 0) red[w] = mr;
    barrier_lgkm();
    float mA = red[0];
    #pragma unroll
    for (int q = 1; q < 5; ++q) mA = fmaxf(mA, red[q]);
    float sv = 0.f;
    if (act && gg == 0) sv = own2 ? (expf(v0-mA)+expf(v1-mA)) : expf(v1-mA);
    #pragma unroll
    for (int o = 32; o >= 1; o >>= 1) sv += __shfl_down(sv, o);
    if (lane == 0 && w < 5) sums_sh[k][w] = sv;
    if (tid == 0) m_sh[k] = mA;
    mprev = mA;
    barrier_lgkm();
  }
  __syncthreads();
  if (tid == 0){
    double dd = 0.0;
    for (int kk = 0; kk <= NSTEP; ++kk){
      float lse;
      if (kk == 0) lse = lse_sh[0];
      else {
        float S = sums_sh[kk][0];
        #pragma unroll
        for (int q = 1; q < 5; ++q) S += sums_sh[kk][q];
        lse = m_sh[kk] + logf(S);
      }
      lse_sh[kk] = lse;
      n_sh[kk] = (float)((double)lse + dd);
      dd += (double)m_sh[kk];
    }
  }
  __syncthreads();
  for (int K = 0; K <= NSTEP; ++K){
    const float Cst = n_sh[K] - lse_sh[68-K];
    for (int e = tid; e < JT; e += 704){
      float* r = outb + (size_t)K*JT + e;
      *r = fmaxf(*r + Cst, -3.0e38f);
    }
  }
  __syncthreads();
  {
    int c = 3, t2 = ls[b];
    float* mpb = out + (size_t)ALPHA_N + (size_t)b*(69*3);
    if (tid == 0){
      mpb[68*3+0] = 3.f; mpb[68*3+1] = 0.f; mpb[68*3+2] = (float)t2;
      mpb[67*3+1] = 0.f;
    }
    const bool vok = tid < JT;
    const int etid = vok ? tid : 0;
    const int im = etid / S1, sm = etid - im*S1;
    float av = vok ? outb[1*JT + tid] : NEGINF;
    for (int r = 1; r <= NSTEP; ++r){
      float avn = NEGINF;
      if (r < NSTEP && vok) avn = outb[(size_t)(r+1)*JT + tid];
      float best = NEGINF; int bidx = 0x7fffffff;
      if (vok){
        float qv;
        if (wsmode >= 1) qv = QW[(size_t)c*QI + (size_t)sm*JT + im*S1 + t2];
        else             qv = Q[(size_t)c*QI + (size_t)im*QJ + sm*S1 + t2];
        const float pv = P[(size_t)(b*C9 + c)*QJ + sm*S1 + t2];
        best = (pv + Tv*qv) + av; bidx = tid;
      }
      #pragma unroll
      for (int o = 32; o >= 1; o >>= 1){
        const float ov = __shfl_down(best, o); const int oi = __shfl_down(bidx, o);
        if (ov > best || (ov == best && oi < bidx)){ best = ov; bidx = oi; }
      }
      if (lane == 0){ sbest[w] = best; sidx[w] = bidx; }
      __syncthreads();
      if (tid == 0){
        float bbv = sbest[0]; int bi = sidx[0];
        #pragma unroll
        for (int q = 1; q < 11; ++q)
          if (sbest[q] > bbv || (sbest[q] == bbv && sidx[q] < bi)){ bbv = sbest[q]; bi = sidx[q]; }
        const int cn = bi / S1, tn = bi - cn*S1;
        mpb[(68-r)*3 + 0] = (float)cn;
        mpb[(68-r)*3 + 2] = (float)tn;
        if (r <= 67) mpb[(67-r)*3 + 1] = (float)(tn - t2);
        sct[0] = cn; sct[1] = tn;
      }
      __syncthreads();
      c = sct[0]; t2 = sct[1];
      av = avn;
    }
  }
}

// ---------------------------------------------------------------------------
extern "C" void kernel_launch(void* const* d_in, const int* in_sizes, int n_in,
                              void* d_out, int out_size, void* d_ws, size_t ws_size,
                              hipStream_t stream)
{
  const float* P  = (const float*)d_in[0];
  const float* Q  = (const float*)d_in[1];
  const float* pi = (const float*)d_in[2];
  const float* T  = (const float*)d_in[3];
  const int*   ls = (const int*)d_in[4];
  float* out = (float*)d_out;
  float* wsf = (float*)d_ws;

  // ws layout (group mode): [QW | XC | FLAGS | QT?]
  const size_t need_base = (size_t)(QTFL + XCFL + FLAGN)*4;
  const size_t need_full = need_base + (size_t)QTFL*4;

  if (ws_size >= need_base){
    float*    QW    = wsf;
    float*    XC    = wsf + QTFL;
    unsigned* FLAGS = (unsigned*)(wsf + QTFL + XCFL);
    float*    QT    = nullptr;
    int qtmode = 1;
    if (ws_size >= need_full){ QT = wsf + QTFL + XCFL + FLAGN; qtmode = 2; }
    zf_kernel<<<18, 256, 0, stream>>>(FLAGS);
    qw_kernel<<<JT, 256, 0, stream>>>(Q, QW);
    if (qtmode >= 2) qtrans_kernel<<<81, 256, 0, stream>>>(Q, QT);
    mega_group<<<NBATCH, 704, 0, stream>>>(P, Q, pi, T, ls, out, QW, QT, XC, FLAGS, qtmode);
  } else {
    int wsmode = 0; float* QW = nullptr;
    if (ws_size >= (size_t)QTFL*4){ wsmode = 1; QW = wsf; }
    if (wsmode >= 1) qw_kernel<<<JT, 256, 0, stream>>>(Q, QW);
    mega_fb<<<NBATCH, 704, 0, stream>>>(P, Q, pi, T, ls, out, QW, wsmode);
  }
}